// Round 8
// baseline (149.347 us; speedup 1.0000x reference)
//
#include <hip/hip_runtime.h>

#define B_ 512
#define L_ 8192
#define N_ 128
#define S_ 256
#define DELIM_ 5
#define T_ 1024          // kernel A: 16 waves/block, 2 blocks/CU
#define NW_ (T_ / 64)

// ---------------------------------------------------------------------------
// Kernel A: per-row scan. Coalesced int4 row read -> LDS + registers; packed
// block scan -> ordered delimiter positions -> chunk table; then per-sentence
// nonzero count (len_sent) via LDS reads + ballots. Emits one packed int per
// sentence: start | (cl<<14) | (len<<23), and len_doc[b]. No otp/mask stores.
// ---------------------------------------------------------------------------
__global__ __launch_bounds__(T_) void scan_kernel(const int* __restrict__ x,
                                                  int* __restrict__ table,
                                                  float* __restrict__ len_doc) {
    const int b = blockIdx.x;
    const int t = threadIdx.x;
    const int lane = t & 63;
    const int w = t >> 6;
    const int* __restrict__ row = x + (size_t)b * L_;

    __shared__ __align__(16) int s_row[L_ + 1];  // row + virtual trailing DELIM
    __shared__ int s_wsum[NW_];
    __shared__ int s_dpos[N_ - 1];
    __shared__ int s_start[N_];
    __shared__ int s_cl[N_];
    __shared__ int s_doc[NW_];

    // phase 1a: coalesced int4 loads; stage into LDS; count delims
    const int4 r0 = ((const int4*)row)[t];        // tokens [4t, 4t+4)
    const int4 r1 = ((const int4*)row)[t + T_];   // tokens [4096+4t, ...)
    ((int4*)s_row)[t] = r0;
    ((int4*)s_row)[t + T_] = r1;
    if (t == 0) s_row[L_] = DELIM_;               // rpad[L]

    const int c0 = (r0.x == DELIM_) + (r0.y == DELIM_) + (r0.z == DELIM_) + (r0.w == DELIM_);
    const int c1 = (r1.x == DELIM_) + (r1.y == DELIM_) + (r1.z == DELIM_) + (r1.w == DELIM_);
    const int packed = c0 | (c1 << 16);

    int v = packed;
#pragma unroll
    for (int d = 1; d < 64; d <<= 1) {
        int n = __shfl_up(v, d, 64);
        if (lane >= d) v += n;
    }
    if (lane == 63) s_wsum[w] = v;
    __syncthreads();

    int woff = 0, tot = 0;
#pragma unroll
    for (int i = 0; i < NW_; ++i) {
        const int sv = s_wsum[i];
        if (i < w) woff += sv;
        tot += sv;
    }
    const int pre = woff + v - packed;
    const int c0tot = tot & 0xffff;
    const int m = c0tot + (tot >> 16);            // total delims in row
    const int off0 = pre & 0xffff;
    const int off1 = c0tot + (pre >> 16);

    // phase 1b: emit ordered delimiter positions from registers
    if (c0 > 0 && off0 < N_ - 1) {
        int o = off0;
        const int p = 4 * t;
        if (r0.x == DELIM_) { if (o < N_ - 1) s_dpos[o] = p;     ++o; }
        if (r0.y == DELIM_) { if (o < N_ - 1) s_dpos[o] = p + 1; ++o; }
        if (r0.z == DELIM_) { if (o < N_ - 1) s_dpos[o] = p + 2; ++o; }
        if (r0.w == DELIM_) { if (o < N_ - 1) s_dpos[o] = p + 3; ++o; }
    }
    if (c1 > 0 && off1 < N_ - 1) {
        int o = off1;
        const int p = 4 * T_ + 4 * t;
        if (r1.x == DELIM_) { if (o < N_ - 1) s_dpos[o] = p;     ++o; }
        if (r1.y == DELIM_) { if (o < N_ - 1) s_dpos[o] = p + 1; ++o; }
        if (r1.z == DELIM_) { if (o < N_ - 1) s_dpos[o] = p + 2; ++o; }
        if (r1.w == DELIM_) { if (o < N_ - 1) s_dpos[o] = p + 3; ++o; }
    }
    __syncthreads();

    // phase 1c: chunk table
    if (t < N_) {
        const int k = t;
        const int mc = (m < N_ - 1) ? m : (N_ - 1);
        int start = 0, cl = 0;
        if (k <= mc) {
            start = (k == 0) ? 0 : (s_dpos[k - 1] + 1);
            const int end = (k < mc) ? s_dpos[k] : L_;
            const int size = end - start + 1;
            cl = (size <= 1) ? 0 : (size < S_ ? size : S_);  // lone delim -> all PAD
        }
        s_start[k] = start;
        s_cl[k] = cl;
    }
    __syncthreads();

    // phase 2: wave w computes len for sentence k = i*NW_ + w, packs table
    int doccnt = 0;
#pragma unroll
    for (int i = 0; i < (N_ / NW_); ++i) {
        const int k = i * NW_ + w;
        const int start = s_start[k];
        const int cl = s_cl[k];
        int len = 0;
#pragma unroll
        for (int j = 0; j < 4; ++j) {
            const int e = 64 * j + lane;                       // stride-1, conflict-free
            const int tok = (e < cl) ? s_row[start + e] : 0;   // start+e <= L_ when e<cl
            len += __popcll(__ballot(tok != 0));
        }
        if (lane == 0) table[b * N_ + k] = start | (cl << 14) | (len << 23);
        doccnt += (len > 0);
    }

    if (lane == 0) s_doc[w] = doccnt;
    __syncthreads();
    if (t == 0) {
        int d = 0;
#pragma unroll
        for (int i = 0; i < NW_; ++i) d += s_doc[i];
        len_doc[b] = (float)d;
    }
}

// ---------------------------------------------------------------------------
// Kernel B: pure streaming fill. One sentence per wave, no LDS/barriers/
// atomics. Block g -> row b = g & 511 (XCD = b%8: per-XCD x working set is
// 64 rows = 4 MB = L2), strip = g >> 9; wave w handles k = strip*4 + w.
// Lane holds 4 consecutive elements -> float4 stores.
// ---------------------------------------------------------------------------
__global__ __launch_bounds__(256) void fill_kernel(const int* __restrict__ x,
                                                   const int* __restrict__ table,
                                                   float* __restrict__ otp,
                                                   float* __restrict__ mask) {
    const int g = blockIdx.x;
    const int b = g & (B_ - 1);
    const int strip = g >> 9;
    const int w = threadIdx.x >> 6;
    const int lane = threadIdx.x & 63;
    const int k = strip * 4 + w;

    const int packed = table[b * N_ + k];  // wave-uniform -> scalar load
    const int start = packed & 0x3fff;
    const int cl = (packed >> 14) & 0x1ff;
    const int len = packed >> 23;

    const int* __restrict__ row = x + (size_t)b * L_;
    const int e0 = lane * 4;
    float tf[4], mf[4];
#pragma unroll
    for (int j = 0; j < 4; ++j) {
        const int e = e0 + j;
        int tok = 0;
        if (e < cl) {
            const int gpos = start + e;
            tok = (gpos < L_) ? row[gpos] : DELIM_;  // rpad[L] = trailing DELIM
        }
        tf[j] = (float)tok;
        mf[j] = (e < len) ? 1.0f : 0.0f;
    }
    const size_t o = (size_t)(b * N_ + k) * S_ + e0;
    *(float4*)(otp + o) = make_float4(tf[0], tf[1], tf[2], tf[3]);
    *(float4*)(mask + o) = make_float4(mf[0], mf[1], mf[2], mf[3]);
}

extern "C" void kernel_launch(void* const* d_in, const int* in_sizes, int n_in,
                              void* d_out, int out_size, void* d_ws, size_t ws_size,
                              hipStream_t stream) {
    const int* x = (const int*)d_in[0];
    float* out = (float*)d_out;

    // d_out layout (flat, return order): otp[B*N*S] | len_doc[B] | mask[B*N*S]
    float* otp = out;
    float* len_doc = out + (size_t)B_ * N_ * S_;
    float* mask = len_doc + B_;

    int* table = (int*)d_ws;  // B*N packed ints (256 KB)

    scan_kernel<<<B_, T_, 0, stream>>>(x, table, len_doc);
    fill_kernel<<<(B_ * N_) / 4, 256, 0, stream>>>(x, table, otp, mask);
}

// Round 9
// 141.927 us; speedup vs baseline: 1.0523x; 1.0523x over previous
//
#include <hip/hip_runtime.h>

#define B_ 512
#define L_ 8192
#define N_ 128
#define S_ 256
#define DELIM_ 5
#define T_ 1024          // 16 waves/block, 2 blocks/CU -> 32 waves/CU
#define NW_ (T_ / 64)

// One block per row.
// Phase 1: coalesced int4 row read -> registers AND LDS (ds_write_b128);
//          packed block scan -> ordered delimiter positions -> chunk table.
// Phase 2: one sentence per wave per iteration; tokens gathered from LDS
//          (stride-1, conflict-free), element layout e = 64*j + lane ->
//          coalesced dword stores. ballot+popc for len_sent. No atomics.
// R8 post-mortem: 2-kernel split regressed (extra launch + table round-trip)
// and signed bit-packing of len=256 corrupted mask. This fused form is best.
__global__ __launch_bounds__(T_) void split_kernel(const int* __restrict__ x,
                                                   float* __restrict__ otp,
                                                   float* __restrict__ len_doc,
                                                   float* __restrict__ mask) {
    const int b = blockIdx.x;
    const int t = threadIdx.x;
    const int lane = t & 63;
    const int w = t >> 6;
    const int* __restrict__ row = x + (size_t)b * L_;

    __shared__ __align__(16) int s_row[L_ + 1];  // row + virtual trailing DELIM
    __shared__ int s_wsum[NW_];
    __shared__ int s_dpos[N_ - 1];  // first 127 delimiter positions (tail merge)
    __shared__ int s_start[N_];
    __shared__ int s_cl[N_];        // copy length: 0 for empty/unused, else min(size, S)
    __shared__ int s_doc[NW_];

    // ---- phase 1a: coalesced int4 loads; stage into LDS; count delims ----
    const int4 r0 = ((const int4*)row)[t];        // tokens [4t, 4t+4)
    const int4 r1 = ((const int4*)row)[t + T_];   // tokens [4096+4t, ...)
    ((int4*)s_row)[t] = r0;                       // ds_write_b128, conflict-free
    ((int4*)s_row)[t + T_] = r1;
    if (t == 0) s_row[L_] = DELIM_;               // rpad[L]

    const int c0 = (r0.x == DELIM_) + (r0.y == DELIM_) + (r0.z == DELIM_) + (r0.w == DELIM_);
    const int c1 = (r1.x == DELIM_) + (r1.y == DELIM_) + (r1.z == DELIM_) + (r1.w == DELIM_);
    const int packed = c0 | (c1 << 16);

    // wave inclusive scan of packed counts
    int v = packed;
#pragma unroll
    for (int d = 1; d < 64; d <<= 1) {
        int n = __shfl_up(v, d, 64);
        if (lane >= d) v += n;
    }
    if (lane == 63) s_wsum[w] = v;
    __syncthreads();

    int woff = 0, tot = 0;
#pragma unroll
    for (int i = 0; i < NW_; ++i) {
        const int sv = s_wsum[i];
        if (i < w) woff += sv;
        tot += sv;
    }
    const int pre = woff + v - packed;          // exclusive prefix (packed)
    const int c0tot = tot & 0xffff;             // total delims in first half
    const int m = c0tot + (tot >> 16);          // total delims in row
    const int off0 = pre & 0xffff;
    const int off1 = c0tot + (pre >> 16);

    // ---- phase 1b: emit ordered delimiter positions from registers ----
    if (c0 > 0 && off0 < N_ - 1) {
        int o = off0;
        const int p = 4 * t;
        if (r0.x == DELIM_) { if (o < N_ - 1) s_dpos[o] = p;     ++o; }
        if (r0.y == DELIM_) { if (o < N_ - 1) s_dpos[o] = p + 1; ++o; }
        if (r0.z == DELIM_) { if (o < N_ - 1) s_dpos[o] = p + 2; ++o; }
        if (r0.w == DELIM_) { if (o < N_ - 1) s_dpos[o] = p + 3; ++o; }
    }
    if (c1 > 0 && off1 < N_ - 1) {
        int o = off1;
        const int p = 4 * T_ + 4 * t;
        if (r1.x == DELIM_) { if (o < N_ - 1) s_dpos[o] = p;     ++o; }
        if (r1.y == DELIM_) { if (o < N_ - 1) s_dpos[o] = p + 1; ++o; }
        if (r1.z == DELIM_) { if (o < N_ - 1) s_dpos[o] = p + 2; ++o; }
        if (r1.w == DELIM_) { if (o < N_ - 1) s_dpos[o] = p + 3; ++o; }
    }
    __syncthreads();

    // ---- phase 1c: chunk table ----
    if (t < N_) {
        const int k = t;
        const int mc = (m < N_ - 1) ? m : (N_ - 1);  // last used chunk index
        int start = 0, cl = 0;
        if (k <= mc) {
            start = (k == 0) ? 0 : (s_dpos[k - 1] + 1);
            const int end = (k < mc) ? s_dpos[k] : L_;  // rpad[L] = trailing DELIM
            const int size = end - start + 1;           // delimiter belongs to its chunk
            cl = (size <= 1) ? 0 : (size < S_ ? size : S_);  // lone delim -> all PAD
        }
        s_start[k] = start;
        s_cl[k] = cl;
    }
    __syncthreads();

    // ---- phase 2: wave w handles sentence k = i*NW_ + w (8 iterations) ----
    float* __restrict__ otp_b = otp + (size_t)b * N_ * S_;
    float* __restrict__ msk_b = mask + (size_t)b * N_ * S_;
    int doccnt = 0;
#pragma unroll
    for (int i = 0; i < (N_ / NW_); ++i) {
        const int k = i * NW_ + w;
        const int start = s_start[k];  // wave-uniform LDS broadcast
        const int cl = s_cl[k];
        float tf[4];
        int len = 0;
#pragma unroll
        for (int j = 0; j < 4; ++j) {
            const int e = 64 * j + lane;          // stride-1 LDS read, conflict-free
            const int tok = (e < cl) ? s_row[start + e] : 0;  // start+e <= L_ when e<cl
            tf[j] = (float)tok;
            len += __popcll(__ballot(tok != 0));  // wave-uniform nonzero count
        }
#pragma unroll
        for (int j = 0; j < 4; ++j) {
            const int e = 64 * j + lane;
            otp_b[(size_t)k * S_ + e] = tf[j];    // coalesced 256B dword store
            msk_b[(size_t)k * S_ + e] = (e < len) ? 1.0f : 0.0f;
        }
        doccnt += (len > 0);
    }

    // ---- len_doc: one LDS reduction per block, no atomics ----
    if (lane == 0) s_doc[w] = doccnt;
    __syncthreads();
    if (t == 0) {
        int d = 0;
#pragma unroll
        for (int i = 0; i < NW_; ++i) d += s_doc[i];
        len_doc[b] = (float)d;
    }
}

extern "C" void kernel_launch(void* const* d_in, const int* in_sizes, int n_in,
                              void* d_out, int out_size, void* d_ws, size_t ws_size,
                              hipStream_t stream) {
    const int* x = (const int*)d_in[0];
    float* out = (float*)d_out;

    // d_out layout (flat, return order): otp[B*N*S] | len_doc[B] | mask[B*N*S]
    float* otp = out;
    float* len_doc = out + (size_t)B_ * N_ * S_;
    float* mask = len_doc + B_;

    split_kernel<<<B_, T_, 0, stream>>>(x, otp, len_doc, mask);
}